// Round 15
// baseline (1142.198 us; speedup 1.0000x reference)
//
#include <hip/hip_runtime.h>
#include <cstdint>
#include <cstddef>

#define DDIM 1536
#define NROWS 6272      // B*P*P = 49*128 exactly
#define NROWPAD 6400
#define MBANK 50000
#define NCOLPAD 50176   // 392*128
#define NRT 49
#define NCT 392
#define NSLOT (NCT * 2) // per-(ct, wn-wave) candidate slots = 784
#define NKT 24          // 1536 / 64  (i8 K-tile = 64)
#define NB 8
#define PP 784
#define HW 224
#define KS 33
#define PAD 16

typedef __attribute__((ext_vector_type(4))) int int4v;
typedef __attribute__((ext_vector_type(4))) float floatx4;

__device__ __forceinline__ unsigned long long u64min(unsigned long long a, unsigned long long b) {
  return a < b ? a : b;
}

__device__ __forceinline__ int reflect224(int i) {
  if (i < 0) i = -i;
  if (i > 223) i = 446 - i;
  return i;
}

// ------- fused convert fp32 -> i8 (scale 16, RNE) + fp32 row norm, BOTH tensors -------
__global__ __launch_bounds__(256) void convnorm_both_kernel(
    const float* __restrict__ mem, const float* __restrict__ emb,
    signed char* __restrict__ mem_q, signed char* __restrict__ emb_q,
    float* __restrict__ ynorm, float* __restrict__ xnorm) {
  int row = blockIdx.x * 4 + (threadIdx.x >> 6);
  int lane = threadIdx.x & 63;
  const float* src;
  int* dst;
  float* norm;
  bool valid;
  int r;
  if (row < NCOLPAD) {
    r = row;
    src = mem + (size_t)r * DDIM;
    dst = (int*)(mem_q + (size_t)r * DDIM);
    norm = ynorm + r;
    valid = (r < MBANK);
  } else {
    r = row - NCOLPAD;
    if (r >= NROWPAD) return;
    src = emb + (size_t)r * DDIM;
    dst = (int*)(emb_q + (size_t)r * DDIM);
    norm = xnorm + r;
    valid = (r < NROWS);
  }
  float s = 0.f;
  if (valid) {
    const float4* s4 = (const float4*)src;
#pragma unroll
    for (int i = 0; i < 6; i++) {
      int d = lane + i * 64;
      float4 v = s4[d];
      s = fmaf(v.x, v.x, s); s = fmaf(v.y, v.y, s);
      s = fmaf(v.z, v.z, s); s = fmaf(v.w, v.w, s);
      int q0 = min(max((int)rintf(v.x * 16.f), -127), 127);
      int q1 = min(max((int)rintf(v.y * 16.f), -127), 127);
      int q2 = min(max((int)rintf(v.z * 16.f), -127), 127);
      int q3 = min(max((int)rintf(v.w * 16.f), -127), 127);
      dst[d] = (q0 & 255) | ((q1 & 255) << 8) | ((q2 & 255) << 16) | ((q3 & 255) << 24);
    }
  } else {
#pragma unroll
    for (int i = 0; i < 6; i++) dst[lane + i * 64] = 0;
  }
  for (int off = 32; off; off >>= 1) s += __shfl_down(s, off, 64);
  if (lane == 0) *norm = s;
}

// ---------------- plain rownorm (fallback path) ----------------
__global__ __launch_bounds__(256) void rownorm_kernel(const float* __restrict__ x,
                                                      float* __restrict__ out, int rows) {
  int row = blockIdx.x;
  if (row >= rows) return;
  const float4* p4 = (const float4*)(x + (size_t)row * DDIM);
  float s = 0.f;
  for (int d = threadIdx.x; d < DDIM / 4; d += 256) {
    float4 v = p4[d];
    s = fmaf(v.x, v.x, s); s = fmaf(v.y, v.y, s);
    s = fmaf(v.z, v.z, s); s = fmaf(v.w, v.w, s);
  }
  for (int off = 32; off; off >>= 1) s += __shfl_down(s, off, 64);
  __shared__ float ls[4];
  int wid = threadIdx.x >> 6, lane = threadIdx.x & 63;
  if (lane == 0) ls[wid] = s;
  __syncthreads();
  if (threadIdx.x == 0) out[row] = ls[0] + ls[1] + ls[2] + ls[3];
}

__global__ void init_u64_kernel(unsigned long long* p, int n) {
  int i = blockIdx.x * 256 + threadIdx.x;
  if (i < n) p[i] = ~0ull;
}

// ====== 128x128 / BK=64 i8 / 4-wave / 4-blocks-per-CU MFMA min-dist (R14-proven) ======
__global__ __launch_bounds__(256, 4) void mindist_mfma_kernel(
    const signed char* __restrict__ Ah, const signed char* __restrict__ Bh,
    const float* __restrict__ xnorm, const float* __restrict__ ynorm,
    unsigned long long* __restrict__ cand) {
  __shared__ char smem[32768];  // A: 2 x 8KB at 0; B: 2 x 8KB at 16384

  const int t = threadIdx.x;
  const int lane = t & 63, wid = t >> 6;
  const int wm = wid >> 1, wn = wid & 1;  // 2M x 2N waves; wave tile 64x64
  const int l15 = lane & 15, g = lane >> 4;

  // bijective XCD swizzle over row-major (rt, ct); 19208 = 8 * 2401 exactly
  const int wg = (blockIdx.x & 7) * 2401 + (blockIdx.x >> 3);
  const int rt = wg / NCT, ct = wg % NCT;
  const int row0 = rt * 128;
  const int c0 = ct * 128;

  // fragment read: row = base + l15 (64B rows); chunk ck = (g ^ ((l15>>1)&3))*16
  const int ck = ((g ^ ((l15 >> 1) & 3)) << 4);
  const int aBase = wm * 4096 + l15 * 64;           // + d*8192 + mi*1024 + ck
  const int bBase = 16384 + wn * 4096 + l15 * 64;   // + d*8192 + nf*1024 + ck

  // staging: thread covers flat 16B chunk f = j*256 + t of a 128-row x 4-chunk tile
  const int cl = (t & 3) ^ ((t >> 3) & 3);
  const signed char* paBase = Ah + (size_t)(row0 + (t >> 2)) * DDIM + cl * 16;
  const signed char* pbBase = Bh + (size_t)(c0 + (t >> 2)) * DDIM + cl * 16;

#define STAGE_KT(kt, d)                                                                  \
  {                                                                                      \
    _Pragma("unroll") for (int j = 0; j < 2; j++) {                                      \
      __builtin_amdgcn_global_load_lds(                                                  \
          (const __attribute__((address_space(1))) void*)(paBase +                       \
              (size_t)(j * 64) * DDIM + (size_t)(kt) * 64),                              \
          (__attribute__((address_space(3))) void*)(smem + (d) * 8192 + j * 4096 +       \
                                                    wid * 1024),                         \
          16, 0, 0);                                                                     \
    }                                                                                    \
    _Pragma("unroll") for (int j = 0; j < 2; j++) {                                      \
      __builtin_amdgcn_global_load_lds(                                                  \
          (const __attribute__((address_space(1))) void*)(pbBase +                       \
              (size_t)(j * 64) * DDIM + (size_t)(kt) * 64),                              \
          (__attribute__((address_space(3))) void*)(smem + 16384 + (d) * 8192 +          \
                                                    j * 4096 + wid * 1024),              \
          16, 0, 0);                                                                     \
    }                                                                                    \
  }

  int4v acc[4][4];  // [mi][nf]; row = wm*64 + mi*16, col = wn*64 + nf*16
  int4v zz = {0, 0, 0, 0};
#pragma unroll
  for (int mi = 0; mi < 4; mi++)
#pragma unroll
    for (int nf = 0; nf < 4; nf++) acc[mi][nf] = zz;

  STAGE_KT(0, 0);
  STAGE_KT(1, 1);

  for (int kt = 0; kt < NKT; ++kt) {
    const int d = kt & 1;
    if (kt < NKT - 1) {
      asm volatile("s_waitcnt vmcnt(4)" ::: "memory");
    } else {
      asm volatile("s_waitcnt vmcnt(0)" ::: "memory");
    }
    __builtin_amdgcn_sched_barrier(0);
    __builtin_amdgcn_s_barrier();
    __builtin_amdgcn_sched_barrier(0);

    const char* sA = smem + d * 8192 + aBase;
    const char* sB = smem + d * 8192 + bBase;

    int4v ra[4], rb[4];
#pragma unroll
    for (int mi = 0; mi < 4; mi++) ra[mi] = *(const int4v*)(sA + mi * 1024 + ck);
#pragma unroll
    for (int nf = 0; nf < 4; nf++) rb[nf] = *(const int4v*)(sB + nf * 1024 + ck);
    __builtin_amdgcn_s_setprio(1);
#pragma unroll
    for (int mi = 0; mi < 4; mi++)
#pragma unroll
      for (int nf = 0; nf < 4; nf++)
        acc[mi][nf] = __builtin_amdgcn_mfma_i32_16x16x64_i8(ra[mi], rb[nf],
                                                            acc[mi][nf], 0, 0, 0);
    __builtin_amdgcn_s_setprio(0);
    __builtin_amdgcn_sched_barrier(0);
    __builtin_amdgcn_s_barrier();  // all reads of dbuf d complete block-wide
    __builtin_amdgcn_sched_barrier(0);
    if (kt < NKT - 2) STAGE_KT(kt + 2, d);  // sole stage site, after the frontier
  }
#undef STAGE_KT

  // epilogue: dsq = xn + yn - acc * 2^-7; shuffle-min; wave-private slot store
  float yn[4];
  int colv[4];
#pragma unroll
  for (int nf = 0; nf < 4; nf++) {
    int col = c0 + wn * 64 + nf * 16 + l15;
    colv[nf] = col;
    yn[nf] = (col < MBANK) ? ynorm[col] : 0.f;
  }
#pragma unroll
  for (int mi = 0; mi < 4; mi++) {
    int rowb = row0 + wm * 64 + mi * 16 + g * 4;
#pragma unroll
    for (int q = 0; q < 4; q++) {
      float xnq = xnorm[rowb + q];
      unsigned long long best = ~0ull;
#pragma unroll
      for (int nf = 0; nf < 4; nf++) {
        if (colv[nf] < MBANK) {
          float dsq = fmaxf(xnq + yn[nf] - (float)acc[mi][nf][q] * 0.0078125f, 0.f);
          unsigned long long pk =
              ((unsigned long long)__float_as_uint(dsq) << 32) | (unsigned)colv[nf];
          best = u64min(best, pk);
        }
      }
#pragma unroll
      for (int mask = 1; mask <= 8; mask <<= 1)
        best = u64min(best, __shfl_xor(best, mask, 64));
      if (l15 == 0 && rowb + q < NROWS)
        cand[(size_t)(rowb + q) * NSLOT + ct * 2 + wn] = best;
    }
  }
}

// -------- gated fp32 re-rank of the 784 per-slot winners (value + exact index) --------
__global__ __launch_bounds__(256) void rerank_kernel(
    const float* __restrict__ emb, const float* __restrict__ mem,
    const float* __restrict__ xnorm, const float* __restrict__ ynorm,
    const unsigned long long* __restrict__ cand, float* __restrict__ ps,
    int* __restrict__ loc) {
  int row = blockIdx.x, t = threadIdx.x;
  int lane = t & 63, wave = t >> 6;
  __shared__ unsigned long long lred[4];
  __shared__ int glist[64];
  __shared__ int gcount;
  __shared__ float gmin;
  const unsigned long long* crow = cand + (size_t)row * NSLOT;
  unsigned long long mn = ~0ull;
  for (int i = t; i < NSLOT; i += 256) mn = u64min(mn, crow[i]);
  for (int off = 32; off; off >>= 1) {
    unsigned long long o = __shfl_down(mn, off, 64);
    mn = u64min(mn, o);
  }
  if (lane == 0) lred[wave] = mn;
  if (t == 0) gcount = 0;
  __syncthreads();
  if (t == 0) {
    unsigned long long m0 = lred[0];
    for (int w = 1; w < 4; w++) m0 = u64min(m0, lred[w]);
    gmin = __uint_as_float((unsigned)(m0 >> 32));
  }
  __syncthreads();
  float gate = gmin + 14.0f;  // ~5 sigma of pairwise i8-dot dsq error
  for (int i = t; i < NSLOT; i += 256) {
    unsigned long long v = crow[i];
    float dq = __uint_as_float((unsigned)(v >> 32));
    if (dq <= gate) {  // NaN (empty slot) fails this
      int idx = atomicAdd(&gcount, 1);
      if (idx < 64) glist[idx] = (int)(v & 0xffffffffu);
    }
  }
  __syncthreads();
  int ng = min(gcount, 64);
  float xnv = xnorm[row];
  const float4* xp = (const float4*)(emb + (size_t)row * DDIM);
  unsigned long long best = ~0ull;
  for (int gi = wave; gi < ng; gi += 4) {
    int col = glist[gi];
    const float4* yp = (const float4*)(mem + (size_t)col * DDIM);
    float s = 0.f;
    for (int d4 = lane; d4 < DDIM / 4; d4 += 64) {
      float4 a = xp[d4], b = yp[d4];
      s = fmaf(a.x, b.x, s); s = fmaf(a.y, b.y, s);
      s = fmaf(a.z, b.z, s); s = fmaf(a.w, b.w, s);
    }
    for (int off = 32; off; off >>= 1) s += __shfl_down(s, off, 64);
    if (lane == 0) {
      float dsq = fmaxf(xnv + ynorm[col] - 2.f * s, 0.f);
      unsigned long long pk =
          ((unsigned long long)__float_as_uint(dsq) << 32) | (unsigned)col;
      best = u64min(best, pk);
    }
  }
  if (lane == 0) lred[wave] = best;
  __syncthreads();
  if (t == 0) {
    unsigned long long b = lred[0];
    for (int w = 1; w < 4; w++) b = u64min(b, lred[w]);
    ps[row] = sqrtf(__uint_as_float((unsigned)(b >> 32)));
    loc[row] = (int)(b & 0xffffffffu);
  }
}

// ============== fallback fp32 min-distance GEMM (ws too small) ==============
#define BM 128
#define BN 128
#define DKC 16
#define FCSPLIT 16
#define FCT ((MBANK + BN - 1) / BN)
#define FCPB ((FCT + FCSPLIT - 1) / FCSPLIT)

__global__ __launch_bounds__(256) void mindist_kernel(
    const float* __restrict__ A, const float* __restrict__ Bm,
    const float* __restrict__ xnorm, const float* __restrict__ ynorm,
    unsigned long long* __restrict__ best) {
  __shared__ float Asf[DKC][BM];
  __shared__ float Bsf[DKC][BN];
  int t = threadIdx.x;
  int tx = t & 15, ty = t >> 4;
  int row0 = blockIdx.x * BM;
  int rloc[8], cloc[8];
#pragma unroll
  for (int i = 0; i < 4; i++) {
    rloc[i] = ty * 4 + i; rloc[i + 4] = 64 + ty * 4 + i;
    cloc[i] = tx * 4 + i; cloc[i + 4] = 64 + tx * 4 + i;
  }
  float xnv[8];
#pragma unroll
  for (int i = 0; i < 8; i++) xnv[i] = xnorm[row0 + rloc[i]];
  unsigned long long bestr[8];
#pragma unroll
  for (int i = 0; i < 8; i++) bestr[i] = ~0ull;
  int ct_begin = blockIdx.y * FCPB;
  int ct_end = ct_begin + FCPB; if (ct_end > FCT) ct_end = FCT;
  for (int ct = ct_begin; ct < ct_end; ++ct) {
    int c0 = ct * BN;
    float acc[8][8];
#pragma unroll
    for (int i = 0; i < 8; i++)
#pragma unroll
      for (int j = 0; j < 8; j++) acc[i][j] = 0.f;
    for (int dk = 0; dk < DDIM; dk += DKC) {
#pragma unroll
      for (int s = 0; s < 2; ++s) {
        int q = t + s * 256;
        int r = q >> 2, c4 = q & 3;
        float4 va = *(const float4*)(A + (size_t)(row0 + r) * DDIM + dk + c4 * 4);
        Asf[c4 * 4 + 0][r] = va.x; Asf[c4 * 4 + 1][r] = va.y;
        Asf[c4 * 4 + 2][r] = va.z; Asf[c4 * 4 + 3][r] = va.w;
        int col = c0 + r;
        float4 vb = make_float4(0.f, 0.f, 0.f, 0.f);
        if (col < MBANK) vb = *(const float4*)(Bm + (size_t)col * DDIM + dk + c4 * 4);
        Bsf[c4 * 4 + 0][r] = vb.x; Bsf[c4 * 4 + 1][r] = vb.y;
        Bsf[c4 * 4 + 2][r] = vb.z; Bsf[c4 * 4 + 3][r] = vb.w;
      }
      __syncthreads();
#pragma unroll
      for (int k = 0; k < DKC; k++) {
        float4 a0 = *(const float4*)&Asf[k][ty * 4];
        float4 a1 = *(const float4*)&Asf[k][64 + ty * 4];
        float4 b0 = *(const float4*)&Bsf[k][tx * 4];
        float4 b1 = *(const float4*)&Bsf[k][64 + tx * 4];
        float av[8] = {a0.x, a0.y, a0.z, a0.w, a1.x, a1.y, a1.z, a1.w};
        float bv[8] = {b0.x, b0.y, b0.z, b0.w, b1.x, b1.y, b1.z, b1.w};
#pragma unroll
        for (int i = 0; i < 8; i++)
#pragma unroll
          for (int j = 0; j < 8; j++) acc[i][j] = fmaf(av[i], bv[j], acc[i][j]);
      }
      __syncthreads();
    }
#pragma unroll
    for (int j = 0; j < 8; j++) {
      int col = c0 + cloc[j];
      if (col < MBANK) {
        float yn = ynorm[col];
#pragma unroll
        for (int i = 0; i < 8; i++) {
          float dsq = fmaxf(xnv[i] + yn - 2.f * acc[i][j], 0.f);
          unsigned long long pk =
              ((unsigned long long)__float_as_uint(dsq) << 32) | (unsigned)col;
          if (pk < bestr[i]) bestr[i] = pk;
        }
      }
    }
  }
#pragma unroll
  for (int i = 0; i < 8; i++) atomicMin(&best[row0 + rloc[i]], bestr[i]);
}

__global__ void unpack_kernel(const unsigned long long* __restrict__ best,
                              float* __restrict__ ps, int* __restrict__ loc) {
  int i = blockIdx.x * 256 + threadIdx.x;
  if (i >= NROWS) return;
  unsigned long long v = best[i];
  ps[i] = sqrtf(__uint_as_float((unsigned)(v >> 32)));
  loc[i] = (int)(v & 0xffffffffu);
}

// ---------------- per-batch argmax ----------------
__global__ __launch_bounds__(256) void argmax_kernel(const float* __restrict__ ps,
                                                     const int* __restrict__ loc,
                                                     float* __restrict__ bscore,
                                                     int* __restrict__ bfrow,
                                                     int* __restrict__ bnn) {
  int b = blockIdx.x, t = threadIdx.x;
  unsigned long long bp = 0;
  for (int p = t; p < PP; p += 256) {
    unsigned long long pk = ((unsigned long long)__float_as_uint(ps[b * PP + p]) << 32) |
                            (unsigned)(0xffffffffu - (unsigned)p);
    if (pk > bp) bp = pk;
  }
  for (int off = 32; off; off >>= 1) {
    unsigned long long o = __shfl_down(bp, off, 64);
    if (o > bp) bp = o;
  }
  __shared__ unsigned long long ls[4];
  int wid = t >> 6, lane = t & 63;
  if (lane == 0) ls[wid] = bp;
  __syncthreads();
  if (t == 0) {
    for (int w = 1; w < 4; w++) if (ls[w] > ls[0]) ls[0] = ls[w];
    unsigned p = 0xffffffffu - (unsigned)(ls[0] & 0xffffffffu);
    bscore[b] = __uint_as_float((unsigned)(ls[0] >> 32));
    bfrow[b] = b * PP + (int)p;
    bnn[b] = loc[b * PP + (int)p];
  }
}

// ---------------- d2: nn_sample vs memory bank ----------------
__global__ __launch_bounds__(256) void d2_kernel(const float* __restrict__ mem,
                                                 const float* __restrict__ ynorm,
                                                 const int* __restrict__ bnn,
                                                 float* __restrict__ d2) {
  __shared__ float nn8[NB][DDIM];
  __shared__ float nnorm[NB];
  for (int e = threadIdx.x; e < NB * DDIM; e += 256) {
    int b = e / DDIM, d = e % DDIM;
    nn8[b][d] = mem[(size_t)bnn[b] * DDIM + d];
  }
  if (threadIdx.x < NB) nnorm[threadIdx.x] = ynorm[bnn[threadIdx.x]];
  __syncthreads();
  int wid = threadIdx.x >> 6, lane = threadIdx.x & 63;
  int gw = blockIdx.x * 4 + wid;
  int nw = gridDim.x * 4;
  for (int m = gw; m < MBANK; m += nw) {
    const float4* mp4 = (const float4*)(mem + (size_t)m * DDIM);
    float acc[NB];
#pragma unroll
    for (int b = 0; b < NB; b++) acc[b] = 0.f;
    for (int d4 = lane; d4 < DDIM / 4; d4 += 64) {
      float4 v = mp4[d4];
#pragma unroll
      for (int b = 0; b < NB; b++) {
        float4 w = *(const float4*)&nn8[b][d4 * 4];
        acc[b] = fmaf(v.x, w.x, acc[b]); acc[b] = fmaf(v.y, w.y, acc[b]);
        acc[b] = fmaf(v.z, w.z, acc[b]); acc[b] = fmaf(v.w, w.w, acc[b]);
      }
    }
    float yn = ynorm[m];
#pragma unroll
    for (int b = 0; b < NB; b++) {
      float r = acc[b];
      for (int off = 32; off; off >>= 1) r += __shfl_down(r, off, 64);
      if (lane == 0) d2[(size_t)b * MBANK + m] = sqrtf(fmaxf(nnorm[b] + yn - 2.f * r, 0.f));
    }
  }
}

// ------- single-pass top-9 + softmax weight + pred score -------
__global__ __launch_bounds__(256) void topk_kernel(
    const float* __restrict__ emb, const float* __restrict__ mem,
    const float* __restrict__ xnorm, const float* __restrict__ ynorm,
    const float* __restrict__ d2, const float* __restrict__ bscore,
    const int* __restrict__ bfrow, float* __restrict__ pred) {
  int b = blockIdx.x, t = threadIdx.x;
  __shared__ unsigned long long ls9[256][9];
  __shared__ float fred[4];
  __shared__ int supp[9];
  __shared__ float d3s[9];
  const float* row = d2 + (size_t)b * MBANK;
  unsigned long long a0 = ~0ull, a1 = ~0ull, a2 = ~0ull, a3 = ~0ull, a4 = ~0ull,
                     a5 = ~0ull, a6 = ~0ull, a7 = ~0ull, a8 = ~0ull;
  for (int m = t; m < MBANK; m += 256) {
    unsigned long long pk = ((unsigned long long)__float_as_uint(row[m]) << 32) | (unsigned)m;
    if (pk < a8) {
      a8 = pk;
      unsigned long long tv;
#define CSWP(x, y) if (y < x) { tv = x; x = y; y = tv; }
      CSWP(a7, a8) CSWP(a6, a7) CSWP(a5, a6) CSWP(a4, a5)
      CSWP(a3, a4) CSWP(a2, a3) CSWP(a1, a2) CSWP(a0, a1)
#undef CSWP
    }
  }
  ls9[t][0] = a0; ls9[t][1] = a1; ls9[t][2] = a2; ls9[t][3] = a3; ls9[t][4] = a4;
  ls9[t][5] = a5; ls9[t][6] = a6; ls9[t][7] = a7; ls9[t][8] = a8;
  __syncthreads();
  for (int s = 128; s >= 1; s >>= 1) {
    if (t < s) {
      unsigned long long outv[9];
      int i = 0, j = 0;
#pragma unroll
      for (int k = 0; k < 9; k++) {
        unsigned long long x = ls9[t][i], y = ls9[t + s][j];
        if (x <= y) { outv[k] = x; i++; } else { outv[k] = y; j++; }
      }
#pragma unroll
      for (int k = 0; k < 9; k++) ls9[t][k] = outv[k];
    }
    __syncthreads();
  }
  if (t < 9) supp[t] = (int)(ls9[0][t] & 0xffffffffu);
  __syncthreads();
  int frow = bfrow[b];
  const float* x = emb + (size_t)frow * DDIM;
  float xnv = xnorm[frow];
  for (int k = 0; k < 9; k++) {
    const float* y = mem + (size_t)supp[k] * DDIM;
    float s = 0.f;
    for (int d = t; d < DDIM; d += 256) s = fmaf(x[d], y[d], s);
    for (int off = 32; off; off >>= 1) s += __shfl_down(s, off, 64);
    if ((t & 63) == 0) fred[t >> 6] = s;
    __syncthreads();
    if (t == 0) {
      float dot = fred[0] + fred[1] + fred[2] + fred[3];
      d3s[k] = sqrtf(fmaxf(xnv - 2.f * dot + ynorm[supp[k]], 0.f));
    }
    __syncthreads();
  }
  if (t == 0) {
    float mx = d3s[0];
    for (int k = 1; k < 9; k++) mx = fmaxf(mx, d3s[k]);
    float sum = 0.f;
    for (int k = 0; k < 9; k++) sum += expf(d3s[k] - mx);
    float w = 1.f - expf(d3s[0] - mx) / sum;
    pred[b] = w * bscore[b];
  }
}

// ------- W = blur(reflect) . upsample(bilinear,clamp): 224x28 operator -------
__global__ __launch_bounds__(256) void wprep_kernel(float* __restrict__ W) {
  int y = threadIdx.x;
  if (y >= HW) return;
  // gaussian normalizer
  float sum = 0.f;
  for (int j = 0; j < KS; j++) {
    float xj = (float)j - (float)(KS - 1) * 0.5f;
    sum += __expf(-(xj * xj) / 32.0f);
  }
  float inv = 1.f / sum;
  for (int r = 0; r < 28; r++) {
    float w = 0.f;
    for (int j = 0; j < KS; j++) {
      float xj = (float)j - (float)(KS - 1) * 0.5f;
      float gj = __expf(-(xj * xj) / 32.0f) * inv;
      int v = reflect224(y - PAD + j);
      float sy = (v + 0.5f) * 0.125f - 0.5f;
      int y0 = (int)floorf(sy);
      float fy = sy - y0;
      int r0 = min(max(y0, 0), 27), r1 = min(max(y0 + 1, 0), 27);
      float u = (r == r0 ? (1.f - fy) : 0.f) + (r == r1 ? fy : 0.f);
      w = fmaf(gj, u, w);
    }
    W[y * 28 + r] = w;
  }
}

// ------- anomaly map: out_b = W . P_b . W^T  (fused resize+blur, exact linear map) -------
__global__ __launch_bounds__(256) void anomap_kernel(const float* __restrict__ ps,
                                                     const float* __restrict__ W,
                                                     float* __restrict__ out) {
  __shared__ float Ps[28 * 28];
  __shared__ float Ws[HW * 28];
  __shared__ float Ts[28 * HW];
  int b = blockIdx.x, t = threadIdx.x;
  for (int i = t; i < 28 * 28; i += 256) Ps[i] = ps[b * PP + i];
  for (int i = t; i < HW * 28; i += 256) Ws[i] = W[i];
  __syncthreads();
  // T[r][x] = sum_c P[r][c] * W[x][c]
  for (int i = t; i < 28 * HW; i += 256) {
    int r = i / HW, x = i % HW;
    float s = 0.f;
#pragma unroll
    for (int c = 0; c < 28; c++) s = fmaf(Ps[r * 28 + c], Ws[x * 28 + c], s);
    Ts[r * HW + x] = s;
  }
  __syncthreads();
  // out[y][x] = sum_r W[y][r] * T[r][x]
  float* ob = out + (size_t)b * HW * HW;
  for (int i = t; i < HW * HW; i += 256) {
    int y = i / HW, x = i % HW;
    float s = 0.f;
#pragma unroll
    for (int r = 0; r < 28; r++) s = fmaf(Ws[y * 28 + r], Ts[r * HW + x], s);
    ob[i] = s;
  }
}

// ---------------- host ----------------
extern "C" void kernel_launch(void* const* d_in, const int* in_sizes, int n_in,
                              void* d_out, int out_size, void* d_ws, size_t ws_size,
                              hipStream_t stream) {
  const float* emb = (const float*)d_in[0];
  const float* mem = (const float*)d_in[1];
  float* out = (float*)d_out;

  char* ws = (char*)d_ws;
  size_t off = 0;
  auto alloc = [&](size_t bytes) -> void* {
    void* p = ws + off;
    off += (bytes + 255) & ~(size_t)255;
    return p;
  };
  float* ynorm = (float*)alloc((size_t)NCOLPAD * 4);
  float* xnorm = (float*)alloc((size_t)NROWPAD * 4);
  unsigned long long* cand =
      (unsigned long long*)alloc((size_t)NROWS * NSLOT * 8);
  float* ps = (float*)alloc(NROWS * 4);
  int* loc = (int*)alloc(NROWS * 4);
  float* bscore = (float*)alloc(NB * 4);
  int* bfrow = (int*)alloc(NB * 4);
  int* bnn = (int*)alloc(NB * 4);
  float* d2 = (float*)alloc((size_t)NB * MBANK * 4);
  float* W = (float*)alloc((size_t)HW * 28 * 4);
  signed char* emb_q = (signed char*)alloc((size_t)NROWPAD * DDIM);
  signed char* mem_q = (signed char*)alloc((size_t)NCOLPAD * DDIM);
  size_t full_need = off;

  bool fast = (ws_size >= full_need);

  if (fast) {
    convnorm_both_kernel<<<(NCOLPAD + NROWPAD) / 4, 256, 0, stream>>>(mem, emb, mem_q,
                                                                      emb_q, ynorm, xnorm);
    mindist_mfma_kernel<<<NRT * NCT, 256, 0, stream>>>(emb_q, mem_q, xnorm, ynorm, cand);
    rerank_kernel<<<NROWS, 256, 0, stream>>>(emb, mem, xnorm, ynorm, cand, ps, loc);
    argmax_kernel<<<NB, 256, 0, stream>>>(ps, loc, bscore, bfrow, bnn);
  } else {
    rownorm_kernel<<<MBANK, 256, 0, stream>>>(mem, ynorm, MBANK);
    rownorm_kernel<<<NROWS, 256, 0, stream>>>(emb, xnorm, NROWS);
    unsigned long long* best = cand;  // alias
    init_u64_kernel<<<(NROWS + 255) / 256, 256, 0, stream>>>(best, NROWS);
    mindist_kernel<<<dim3(NROWS / BM, FCSPLIT), 256, 0, stream>>>(emb, mem, xnorm, ynorm,
                                                                  best);
    unpack_kernel<<<(NROWS + 255) / 256, 256, 0, stream>>>(best, ps, loc);
    argmax_kernel<<<NB, 256, 0, stream>>>(ps, loc, bscore, bfrow, bnn);
  }

  d2_kernel<<<1200, 256, 0, stream>>>(mem, ynorm, bnn, d2);
  topk_kernel<<<NB, 256, 0, stream>>>(emb, mem, xnorm, ynorm, d2, bscore, bfrow,
                                      out + (size_t)NB * HW * HW);
  wprep_kernel<<<1, 256, 0, stream>>>(W);
  anomap_kernel<<<NB, 256, 0, stream>>>(ps, W, out);
}

// Round 16
// 1010.847 us; speedup vs baseline: 1.1299x; 1.1299x over previous
//
#include <hip/hip_runtime.h>
#include <cstdint>
#include <cstddef>

#define DDIM 1536
#define NROWS 6272      // B*P*P = 49*128 exactly
#define NROWPAD 6400
#define MBANK 50000
#define NCOLPAD 50176   // 392*128
#define NRT 49
#define NCT 392
#define NSLOT (NCT * 2) // per-(ct, wn-wave) candidate slots = 784
#define NKT 24          // 1536 / 64  (i8 K-tile = 64)
#define NB 8
#define PP 784
#define HW 224
#define KS 33
#define PAD 16

typedef __attribute__((ext_vector_type(4))) int int4v;
typedef __attribute__((ext_vector_type(4))) float floatx4;

__device__ __forceinline__ unsigned long long u64min(unsigned long long a, unsigned long long b) {
  return a < b ? a : b;
}

// ---------------- fused convert fp32 -> i8 (scale 16, RNE) + fp32 row norm ----------------
__global__ __launch_bounds__(256) void convnorm8_kernel(const float* __restrict__ in,
                                                        signed char* __restrict__ out,
                                                        float* __restrict__ norm,
                                                        int valid_rows, int total_rows) {
  int row = blockIdx.x * 4 + (threadIdx.x >> 6);
  int lane = threadIdx.x & 63;
  if (row >= total_rows) return;
  int* dst = (int*)(out + (size_t)row * DDIM);
  float s = 0.f;
  if (row < valid_rows) {
    const float4* src = (const float4*)(in + (size_t)row * DDIM);
#pragma unroll
    for (int i = 0; i < 6; i++) {
      int d = lane + i * 64;
      float4 v = src[d];
      s = fmaf(v.x, v.x, s); s = fmaf(v.y, v.y, s);
      s = fmaf(v.z, v.z, s); s = fmaf(v.w, v.w, s);
      int q0 = min(max((int)rintf(v.x * 16.f), -127), 127);
      int q1 = min(max((int)rintf(v.y * 16.f), -127), 127);
      int q2 = min(max((int)rintf(v.z * 16.f), -127), 127);
      int q3 = min(max((int)rintf(v.w * 16.f), -127), 127);
      dst[d] = (q0 & 255) | ((q1 & 255) << 8) | ((q2 & 255) << 16) | ((q3 & 255) << 24);
    }
  } else {
#pragma unroll
    for (int i = 0; i < 6; i++) dst[lane + i * 64] = 0;
  }
  for (int off = 32; off; off >>= 1) s += __shfl_down(s, off, 64);
  if (lane == 0) norm[row] = s;
}

// ---------------- plain rownorm (fallback path) ----------------
__global__ __launch_bounds__(256) void rownorm_kernel(const float* __restrict__ x,
                                                      float* __restrict__ out, int rows) {
  int row = blockIdx.x;
  if (row >= rows) return;
  const float4* p4 = (const float4*)(x + (size_t)row * DDIM);
  float s = 0.f;
  for (int d = threadIdx.x; d < DDIM / 4; d += 256) {
    float4 v = p4[d];
    s = fmaf(v.x, v.x, s); s = fmaf(v.y, v.y, s);
    s = fmaf(v.z, v.z, s); s = fmaf(v.w, v.w, s);
  }
  for (int off = 32; off; off >>= 1) s += __shfl_down(s, off, 64);
  __shared__ float ls[4];
  int wid = threadIdx.x >> 6, lane = threadIdx.x & 63;
  if (lane == 0) ls[wid] = s;
  __syncthreads();
  if (threadIdx.x == 0) out[row] = ls[0] + ls[1] + ls[2] + ls[3];
}

__global__ void init_u64_kernel(unsigned long long* p, int n) {
  int i = blockIdx.x * 256 + threadIdx.x;
  if (i < n) p[i] = ~0ull;
}

// ====== 128x128 / BK=64 i8 / 4-wave / 4-blocks-per-CU MFMA min-dist ======
// 64B LDS rows, swizzle c = g ^ ((row>>1)&3): exactly 2 lanes per (parity,chunk) slot
// per 16-lane group — the measured-free 2-way structure from R12. 32KB LDS -> 4 blk/CU.
// Staging: linear LDS dest + pre-swizzled source; sole stage site after full barrier.
__global__ __launch_bounds__(256, 4) void mindist_mfma_kernel(
    const signed char* __restrict__ Ah, const signed char* __restrict__ Bh,
    const float* __restrict__ xnorm, const float* __restrict__ ynorm,
    unsigned long long* __restrict__ cand) {
  __shared__ char smem[32768];  // A: 2 x 8KB at 0; B: 2 x 8KB at 16384

  const int t = threadIdx.x;
  const int lane = t & 63, wid = t >> 6;
  const int wm = wid >> 1, wn = wid & 1;  // 2M x 2N waves; wave tile 64x64
  const int l15 = lane & 15, g = lane >> 4;

  // bijective XCD swizzle over row-major (rt, ct); 19208 = 8 * 2401 exactly
  const int wg = (blockIdx.x & 7) * 2401 + (blockIdx.x >> 3);
  const int rt = wg / NCT, ct = wg % NCT;
  const int row0 = rt * 128;
  const int c0 = ct * 128;

  // fragment read: row = base + l15 (64B rows); chunk ck = (g ^ ((l15>>1)&3))*16
  const int ck = ((g ^ ((l15 >> 1) & 3)) << 4);
  const int aBase = wm * 4096 + l15 * 64;           // + d*8192 + mi*1024 + ck
  const int bBase = 16384 + wn * 4096 + l15 * 64;   // + d*8192 + nf*1024 + ck

  // staging: thread covers flat 16B chunk f = j*256 + t of a 128-row x 4-chunk tile
  // r = f>>2 = j*64 + (t>>2); phys = t&3; logical cl = (t&3)^((t>>3)&3)
  const int cl = (t & 3) ^ ((t >> 3) & 3);
  const signed char* paBase = Ah + (size_t)(row0 + (t >> 2)) * DDIM + cl * 16;
  const signed char* pbBase = Bh + (size_t)(c0 + (t >> 2)) * DDIM + cl * 16;

#define STAGE_KT(kt, d)                                                                  \
  {                                                                                      \
    _Pragma("unroll") for (int j = 0; j < 2; j++) {                                      \
      __builtin_amdgcn_global_load_lds(                                                  \
          (const __attribute__((address_space(1))) void*)(paBase +                       \
              (size_t)(j * 64) * DDIM + (size_t)(kt) * 64),                              \
          (__attribute__((address_space(3))) void*)(smem + (d) * 8192 + j * 4096 +       \
                                                    wid * 1024),                         \
          16, 0, 0);                                                                     \
    }                                                                                    \
    _Pragma("unroll") for (int j = 0; j < 2; j++) {                                      \
      __builtin_amdgcn_global_load_lds(                                                  \
          (const __attribute__((address_space(1))) void*)(pbBase +                       \
              (size_t)(j * 64) * DDIM + (size_t)(kt) * 64),                              \
          (__attribute__((address_space(3))) void*)(smem + 16384 + (d) * 8192 +          \
                                                    j * 4096 + wid * 1024),              \
          16, 0, 0);                                                                     \
    }                                                                                    \
  }

  int4v acc[4][4];  // [mi][nf]; row = wm*64 + mi*16, col = wn*64 + nf*16
  int4v zz = {0, 0, 0, 0};
#pragma unroll
  for (int mi = 0; mi < 4; mi++)
#pragma unroll
    for (int nf = 0; nf < 4; nf++) acc[mi][nf] = zz;

  STAGE_KT(0, 0);
  STAGE_KT(1, 1);

  for (int kt = 0; kt < NKT; ++kt) {
    const int d = kt & 1;
    if (kt < NKT - 1) {
      asm volatile("s_waitcnt vmcnt(4)" ::: "memory");
    } else {
      asm volatile("s_waitcnt vmcnt(0)" ::: "memory");
    }
    __builtin_amdgcn_sched_barrier(0);
    __builtin_amdgcn_s_barrier();
    __builtin_amdgcn_sched_barrier(0);

    const char* sA = smem + d * 8192 + aBase;
    const char* sB = smem + d * 8192 + bBase;

    int4v ra[4], rb[4];
#pragma unroll
    for (int mi = 0; mi < 4; mi++) ra[mi] = *(const int4v*)(sA + mi * 1024 + ck);
#pragma unroll
    for (int nf = 0; nf < 4; nf++) rb[nf] = *(const int4v*)(sB + nf * 1024 + ck);
    __builtin_amdgcn_s_setprio(1);
#pragma unroll
    for (int mi = 0; mi < 4; mi++)
#pragma unroll
      for (int nf = 0; nf < 4; nf++)
        acc[mi][nf] = __builtin_amdgcn_mfma_i32_16x16x64_i8(ra[mi], rb[nf],
                                                            acc[mi][nf], 0, 0, 0);
    __builtin_amdgcn_s_setprio(0);
    __builtin_amdgcn_sched_barrier(0);
    __builtin_amdgcn_s_barrier();  // all reads of dbuf d complete block-wide
    __builtin_amdgcn_sched_barrier(0);
    if (kt < NKT - 2) STAGE_KT(kt + 2, d);  // sole stage site, after the frontier
  }
#undef STAGE_KT

  // epilogue: dsq = xn + yn - acc * 2^-7; shuffle-min over this wave's 64 cols;
  // store into wave-private slot cand[row][ct*2 + wn] — exactly one writer.
  float yn[4];
  int colv[4];
#pragma unroll
  for (int nf = 0; nf < 4; nf++) {
    int col = c0 + wn * 64 + nf * 16 + l15;
    colv[nf] = col;
    yn[nf] = (col < MBANK) ? ynorm[col] : 0.f;
  }
#pragma unroll
  for (int mi = 0; mi < 4; mi++) {
    int rowb = row0 + wm * 64 + mi * 16 + g * 4;
#pragma unroll
    for (int q = 0; q < 4; q++) {
      float xnq = xnorm[rowb + q];
      unsigned long long best = ~0ull;
#pragma unroll
      for (int nf = 0; nf < 4; nf++) {
        if (colv[nf] < MBANK) {
          float dsq = fmaxf(xnq + yn[nf] - (float)acc[mi][nf][q] * 0.0078125f, 0.f);
          unsigned long long pk =
              ((unsigned long long)__float_as_uint(dsq) << 32) | (unsigned)colv[nf];
          best = u64min(best, pk);
        }
      }
#pragma unroll
      for (int mask = 1; mask <= 8; mask <<= 1)
        best = u64min(best, __shfl_xor(best, mask, 64));
      if (l15 == 0 && rowb + q < NROWS)
        cand[(size_t)(rowb + q) * NSLOT + ct * 2 + wn] = best;
    }
  }
}

// -------- gated fp32 re-rank of the 784 per-slot winners (value + exact index) --------
__global__ __launch_bounds__(256) void rerank_kernel(
    const float* __restrict__ emb, const float* __restrict__ mem,
    const float* __restrict__ xnorm, const float* __restrict__ ynorm,
    const unsigned long long* __restrict__ cand, float* __restrict__ ps,
    int* __restrict__ loc) {
  int row = blockIdx.x, t = threadIdx.x;
  int lane = t & 63, wave = t >> 6;
  __shared__ unsigned long long lred[4];
  __shared__ int glist[64];
  __shared__ int gcount;
  __shared__ float gmin;
  const unsigned long long* crow = cand + (size_t)row * NSLOT;
  unsigned long long mn = ~0ull;
  for (int i = t; i < NSLOT; i += 256) mn = u64min(mn, crow[i]);
  for (int off = 32; off; off >>= 1) {
    unsigned long long o = __shfl_down(mn, off, 64);
    mn = u64min(mn, o);
  }
  if (lane == 0) lred[wave] = mn;
  if (t == 0) gcount = 0;
  __syncthreads();
  if (t == 0) {
    unsigned long long m0 = lred[0];
    for (int w = 1; w < 4; w++) m0 = u64min(m0, lred[w]);
    gmin = __uint_as_float((unsigned)(m0 >> 32));
  }
  __syncthreads();
  float gate = gmin + 14.0f;  // ~5 sigma of pairwise i8-dot dsq error
  for (int i = t; i < NSLOT; i += 256) {
    unsigned long long v = crow[i];
    float dq = __uint_as_float((unsigned)(v >> 32));
    if (dq <= gate) {  // NaN (empty slot) fails this
      int idx = atomicAdd(&gcount, 1);
      if (idx < 64) glist[idx] = (int)(v & 0xffffffffu);
    }
  }
  __syncthreads();
  int ng = min(gcount, 64);
  float xnv = xnorm[row];
  const float4* xp = (const float4*)(emb + (size_t)row * DDIM);
  unsigned long long best = ~0ull;
  for (int gi = wave; gi < ng; gi += 4) {
    int col = glist[gi];
    const float4* yp = (const float4*)(mem + (size_t)col * DDIM);
    float s = 0.f;
    for (int d4 = lane; d4 < DDIM / 4; d4 += 64) {
      float4 a = xp[d4], b = yp[d4];
      s = fmaf(a.x, b.x, s); s = fmaf(a.y, b.y, s);
      s = fmaf(a.z, b.z, s); s = fmaf(a.w, b.w, s);
    }
    for (int off = 32; off; off >>= 1) s += __shfl_down(s, off, 64);
    if (lane == 0) {
      float dsq = fmaxf(xnv + ynorm[col] - 2.f * s, 0.f);
      unsigned long long pk =
          ((unsigned long long)__float_as_uint(dsq) << 32) | (unsigned)col;
      best = u64min(best, pk);
    }
  }
  if (lane == 0) lred[wave] = best;
  __syncthreads();
  if (t == 0) {
    unsigned long long b = lred[0];
    for (int w = 1; w < 4; w++) b = u64min(b, lred[w]);
    ps[row] = sqrtf(__uint_as_float((unsigned)(b >> 32)));
    loc[row] = (int)(b & 0xffffffffu);
  }
}

// ============== fallback fp32 min-distance GEMM (ws too small) ==============
#define BM 128
#define BN 128
#define DKC 16
#define FCSPLIT 16
#define FCT ((MBANK + BN - 1) / BN)
#define FCPB ((FCT + FCSPLIT - 1) / FCSPLIT)

__global__ __launch_bounds__(256) void mindist_kernel(
    const float* __restrict__ A, const float* __restrict__ Bm,
    const float* __restrict__ xnorm, const float* __restrict__ ynorm,
    unsigned long long* __restrict__ best) {
  __shared__ float Asf[DKC][BM];
  __shared__ float Bsf[DKC][BN];
  int t = threadIdx.x;
  int tx = t & 15, ty = t >> 4;
  int row0 = blockIdx.x * BM;
  int rloc[8], cloc[8];
#pragma unroll
  for (int i = 0; i < 4; i++) {
    rloc[i] = ty * 4 + i; rloc[i + 4] = 64 + ty * 4 + i;
    cloc[i] = tx * 4 + i; cloc[i + 4] = 64 + tx * 4 + i;
  }
  float xnv[8];
#pragma unroll
  for (int i = 0; i < 8; i++) xnv[i] = xnorm[row0 + rloc[i]];
  unsigned long long bestr[8];
#pragma unroll
  for (int i = 0; i < 8; i++) bestr[i] = ~0ull;
  int ct_begin = blockIdx.y * FCPB;
  int ct_end = ct_begin + FCPB; if (ct_end > FCT) ct_end = FCT;
  for (int ct = ct_begin; ct < ct_end; ++ct) {
    int c0 = ct * BN;
    float acc[8][8];
#pragma unroll
    for (int i = 0; i < 8; i++)
#pragma unroll
      for (int j = 0; j < 8; j++) acc[i][j] = 0.f;
    for (int dk = 0; dk < DDIM; dk += DKC) {
#pragma unroll
      for (int s = 0; s < 2; ++s) {
        int q = t + s * 256;
        int r = q >> 2, c4 = q & 3;
        float4 va = *(const float4*)(A + (size_t)(row0 + r) * DDIM + dk + c4 * 4);
        Asf[c4 * 4 + 0][r] = va.x; Asf[c4 * 4 + 1][r] = va.y;
        Asf[c4 * 4 + 2][r] = va.z; Asf[c4 * 4 + 3][r] = va.w;
        int col = c0 + r;
        float4 vb = make_float4(0.f, 0.f, 0.f, 0.f);
        if (col < MBANK) vb = *(const float4*)(Bm + (size_t)col * DDIM + dk + c4 * 4);
        Bsf[c4 * 4 + 0][r] = vb.x; Bsf[c4 * 4 + 1][r] = vb.y;
        Bsf[c4 * 4 + 2][r] = vb.z; Bsf[c4 * 4 + 3][r] = vb.w;
      }
      __syncthreads();
#pragma unroll
      for (int k = 0; k < DKC; k++) {
        float4 a0 = *(const float4*)&Asf[k][ty * 4];
        float4 a1 = *(const float4*)&Asf[k][64 + ty * 4];
        float4 b0 = *(const float4*)&Bsf[k][tx * 4];
        float4 b1 = *(const float4*)&Bsf[k][64 + tx * 4];
        float av[8] = {a0.x, a0.y, a0.z, a0.w, a1.x, a1.y, a1.z, a1.w};
        float bv[8] = {b0.x, b0.y, b0.z, b0.w, b1.x, b1.y, b1.z, b1.w};
#pragma unroll
        for (int i = 0; i < 8; i++)
#pragma unroll
          for (int j = 0; j < 8; j++) acc[i][j] = fmaf(av[i], bv[j], acc[i][j]);
      }
      __syncthreads();
    }
#pragma unroll
    for (int j = 0; j < 8; j++) {
      int col = c0 + cloc[j];
      if (col < MBANK) {
        float yn = ynorm[col];
#pragma unroll
        for (int i = 0; i < 8; i++) {
          float dsq = fmaxf(xnv[i] + yn - 2.f * acc[i][j], 0.f);
          unsigned long long pk =
              ((unsigned long long)__float_as_uint(dsq) << 32) | (unsigned)col;
          if (pk < bestr[i]) bestr[i] = pk;
        }
      }
    }
  }
#pragma unroll
  for (int i = 0; i < 8; i++) atomicMin(&best[row0 + rloc[i]], bestr[i]);
}

__global__ void unpack_kernel(const unsigned long long* __restrict__ best,
                              float* __restrict__ ps, int* __restrict__ loc) {
  int i = blockIdx.x * 256 + threadIdx.x;
  if (i >= NROWS) return;
  unsigned long long v = best[i];
  ps[i] = sqrtf(__uint_as_float((unsigned)(v >> 32)));
  loc[i] = (int)(v & 0xffffffffu);
}

// ---------------- per-batch argmax ----------------
__global__ __launch_bounds__(256) void argmax_kernel(const float* __restrict__ ps,
                                                     const int* __restrict__ loc,
                                                     float* __restrict__ bscore,
                                                     int* __restrict__ bfrow,
                                                     int* __restrict__ bnn) {
  int b = blockIdx.x, t = threadIdx.x;
  unsigned long long bp = 0;
  for (int p = t; p < PP; p += 256) {
    unsigned long long pk = ((unsigned long long)__float_as_uint(ps[b * PP + p]) << 32) |
                            (unsigned)(0xffffffffu - (unsigned)p);
    if (pk > bp) bp = pk;
  }
  for (int off = 32; off; off >>= 1) {
    unsigned long long o = __shfl_down(bp, off, 64);
    if (o > bp) bp = o;
  }
  __shared__ unsigned long long ls[4];
  int wid = t >> 6, lane = t & 63;
  if (lane == 0) ls[wid] = bp;
  __syncthreads();
  if (t == 0) {
    for (int w = 1; w < 4; w++) if (ls[w] > ls[0]) ls[0] = ls[w];
    unsigned p = 0xffffffffu - (unsigned)(ls[0] & 0xffffffffu);
    bscore[b] = __uint_as_float((unsigned)(ls[0] >> 32));
    bfrow[b] = b * PP + (int)p;
    bnn[b] = loc[b * PP + (int)p];
  }
}

// ---------------- d2: nn_sample vs memory bank ----------------
__global__ __launch_bounds__(256) void d2_kernel(const float* __restrict__ mem,
                                                 const float* __restrict__ ynorm,
                                                 const int* __restrict__ bnn,
                                                 float* __restrict__ d2) {
  __shared__ float nn8[NB][DDIM];
  __shared__ float nnorm[NB];
  for (int e = threadIdx.x; e < NB * DDIM; e += 256) {
    int b = e / DDIM, d = e % DDIM;
    nn8[b][d] = mem[(size_t)bnn[b] * DDIM + d];
  }
  if (threadIdx.x < NB) nnorm[threadIdx.x] = ynorm[bnn[threadIdx.x]];
  __syncthreads();
  int wid = threadIdx.x >> 6, lane = threadIdx.x & 63;
  int gw = blockIdx.x * 4 + wid;
  int nw = gridDim.x * 4;
  for (int m = gw; m < MBANK; m += nw) {
    const float4* mp4 = (const float4*)(mem + (size_t)m * DDIM);
    float acc[NB];
#pragma unroll
    for (int b = 0; b < NB; b++) acc[b] = 0.f;
    for (int d4 = lane; d4 < DDIM / 4; d4 += 64) {
      float4 v = mp4[d4];
#pragma unroll
      for (int b = 0; b < NB; b++) {
        float4 w = *(const float4*)&nn8[b][d4 * 4];
        acc[b] = fmaf(v.x, w.x, acc[b]); acc[b] = fmaf(v.y, w.y, acc[b]);
        acc[b] = fmaf(v.z, w.z, acc[b]); acc[b] = fmaf(v.w, w.w, acc[b]);
      }
    }
    float yn = ynorm[m];
#pragma unroll
    for (int b = 0; b < NB; b++) {
      float r = acc[b];
      for (int off = 32; off; off >>= 1) r += __shfl_down(r, off, 64);
      if (lane == 0) d2[(size_t)b * MBANK + m] = sqrtf(fmaxf(nnorm[b] + yn - 2.f * r, 0.f));
    }
  }
}

// ------- single-pass top-9 + softmax weight + pred score -------
__global__ __launch_bounds__(256) void topk_kernel(
    const float* __restrict__ emb, const float* __restrict__ mem,
    const float* __restrict__ xnorm, const float* __restrict__ ynorm,
    const float* __restrict__ d2, const float* __restrict__ bscore,
    const int* __restrict__ bfrow, float* __restrict__ pred) {
  int b = blockIdx.x, t = threadIdx.x;
  __shared__ unsigned long long ls9[256][9];
  __shared__ float fred[4];
  __shared__ int supp[9];
  __shared__ float d3s[9];
  const float* row = d2 + (size_t)b * MBANK;
  unsigned long long a0 = ~0ull, a1 = ~0ull, a2 = ~0ull, a3 = ~0ull, a4 = ~0ull,
                     a5 = ~0ull, a6 = ~0ull, a7 = ~0ull, a8 = ~0ull;
  for (int m = t; m < MBANK; m += 256) {
    unsigned long long pk = ((unsigned long long)__float_as_uint(row[m]) << 32) | (unsigned)m;
    if (pk < a8) {
      a8 = pk;
      unsigned long long tv;
#define CSWP(x, y) if (y < x) { tv = x; x = y; y = tv; }
      CSWP(a7, a8) CSWP(a6, a7) CSWP(a5, a6) CSWP(a4, a5)
      CSWP(a3, a4) CSWP(a2, a3) CSWP(a1, a2) CSWP(a0, a1)
#undef CSWP
    }
  }
  ls9[t][0] = a0; ls9[t][1] = a1; ls9[t][2] = a2; ls9[t][3] = a3; ls9[t][4] = a4;
  ls9[t][5] = a5; ls9[t][6] = a6; ls9[t][7] = a7; ls9[t][8] = a8;
  __syncthreads();
  for (int s = 128; s >= 1; s >>= 1) {
    if (t < s) {
      unsigned long long outv[9];
      int i = 0, j = 0;
#pragma unroll
      for (int k = 0; k < 9; k++) {
        unsigned long long x = ls9[t][i], y = ls9[t + s][j];
        if (x <= y) { outv[k] = x; i++; } else { outv[k] = y; j++; }
      }
#pragma unroll
      for (int k = 0; k < 9; k++) ls9[t][k] = outv[k];
    }
    __syncthreads();
  }
  if (t < 9) supp[t] = (int)(ls9[0][t] & 0xffffffffu);
  __syncthreads();
  int frow = bfrow[b];
  const float* x = emb + (size_t)frow * DDIM;
  float xnv = xnorm[frow];
  for (int k = 0; k < 9; k++) {
    const float* y = mem + (size_t)supp[k] * DDIM;
    float s = 0.f;
    for (int d = t; d < DDIM; d += 256) s = fmaf(x[d], y[d], s);
    for (int off = 32; off; off >>= 1) s += __shfl_down(s, off, 64);
    if ((t & 63) == 0) fred[t >> 6] = s;
    __syncthreads();
    if (t == 0) {
      float dot = fred[0] + fred[1] + fred[2] + fred[3];
      d3s[k] = sqrtf(fmaxf(xnv - 2.f * dot + ynorm[supp[k]], 0.f));
    }
    __syncthreads();
  }
  if (t == 0) {
    float mx = d3s[0];
    for (int k = 1; k < 9; k++) mx = fmaxf(mx, d3s[k]);
    float sum = 0.f;
    for (int k = 0; k < 9; k++) sum += expf(d3s[k] - mx);
    float w = 1.f - expf(d3s[0] - mx) / sum;
    pred[b] = w * bscore[b];
  }
}

// ---------------- gaussian weights ----------------
__global__ void gauss_kernel(float* __restrict__ g) {
  __shared__ float tmp[KS];
  int t = threadIdx.x;
  if (t < KS) {
    float x = (float)t - (float)(KS - 1) * 0.5f;
    tmp[t] = __expf(-(x * x) / 32.0f);
  }
  __syncthreads();
  if (t == 0) {
    float s = 0.f;
    for (int j = 0; j < KS; j++) s += tmp[j];
    for (int j = 0; j < KS; j++) g[j] = tmp[j] / s;
  }
}

// ---------------- bilinear resize 28 -> 224 ----------------
__global__ __launch_bounds__(256) void resize_kernel(const float* __restrict__ ps,
                                                     float* __restrict__ out) {
  int idx = blockIdx.x * 256 + threadIdx.x;
  if (idx >= NB * HW * HW) return;
  int x = idx % HW, y = (idx / HW) % HW, b = idx / (HW * HW);
  float sx = (x + 0.5f) * 0.125f - 0.5f;
  float sy = (y + 0.5f) * 0.125f - 0.5f;
  int x0 = (int)floorf(sx), y0 = (int)floorf(sy);
  float fx = sx - x0, fy = sy - y0;
  int x0c = min(max(x0, 0), 27), x1c = min(max(x0 + 1, 0), 27);
  int y0c = min(max(y0, 0), 27), y1c = min(max(y0 + 1, 0), 27);
  const float* p = ps + b * PP;
  float v00 = p[y0c * 28 + x0c], v01 = p[y0c * 28 + x1c];
  float v10 = p[y1c * 28 + x0c], v11 = p[y1c * 28 + x1c];
  out[idx] = v00 * (1.f - fy) * (1.f - fx) + v01 * (1.f - fy) * fx +
             v10 * fy * (1.f - fx) + v11 * fy * fx;
}

// ---------------- separable gaussian blur, reflect padding ----------------
__device__ __forceinline__ int reflect224(int i) {
  if (i < 0) i = -i;
  if (i > 223) i = 446 - i;
  return i;
}

__global__ __launch_bounds__(256) void blurv_kernel(const float* __restrict__ in,
                                                    const float* __restrict__ g,
                                                    float* __restrict__ out) {
  __shared__ float gk[KS];
  if (threadIdx.x < KS) gk[threadIdx.x] = g[threadIdx.x];
  __syncthreads();
  int idx = blockIdx.x * 256 + threadIdx.x;
  if (idx >= NB * HW * HW) return;
  int x = idx % HW, y = (idx / HW) % HW, b = idx / (HW * HW);
  const float* base = in + (size_t)b * HW * HW;
  float s = 0.f;
#pragma unroll
  for (int j = 0; j < KS; j++) {
    int yy = reflect224(y - PAD + j);
    s = fmaf(gk[j], base[yy * HW + x], s);
  }
  out[idx] = s;
}

__global__ __launch_bounds__(256) void blurh_kernel(const float* __restrict__ in,
                                                    const float* __restrict__ g,
                                                    float* __restrict__ out) {
  __shared__ float gk[KS];
  if (threadIdx.x < KS) gk[threadIdx.x] = g[threadIdx.x];
  __syncthreads();
  int idx = blockIdx.x * 256 + threadIdx.x;
  if (idx >= NB * HW * HW) return;
  int x = idx % HW, y = (idx / HW) % HW, b = idx / (HW * HW);
  const float* base = in + (size_t)b * HW * HW;
  float s = 0.f;
#pragma unroll
  for (int j = 0; j < KS; j++) {
    int xx = reflect224(x - PAD + j);
    s = fmaf(gk[j], base[y * HW + xx], s);
  }
  out[idx] = s;
}

// ---------------- host ----------------
extern "C" void kernel_launch(void* const* d_in, const int* in_sizes, int n_in,
                              void* d_out, int out_size, void* d_ws, size_t ws_size,
                              hipStream_t stream) {
  const float* emb = (const float*)d_in[0];
  const float* mem = (const float*)d_in[1];
  float* out = (float*)d_out;

  char* ws = (char*)d_ws;
  size_t off = 0;
  auto alloc = [&](size_t bytes) -> void* {
    void* p = ws + off;
    off += (bytes + 255) & ~(size_t)255;
    return p;
  };
  float* ynorm = (float*)alloc((size_t)NCOLPAD * 4);
  float* xnorm = (float*)alloc((size_t)NROWPAD * 4);
  unsigned long long* cand =
      (unsigned long long*)alloc((size_t)NROWS * NSLOT * 8);
  float* ps = (float*)alloc(NROWS * 4);
  int* loc = (int*)alloc(NROWS * 4);
  float* bscore = (float*)alloc(NB * 4);
  int* bfrow = (int*)alloc(NB * 4);
  int* bnn = (int*)alloc(NB * 4);
  float* d2 = (float*)alloc((size_t)NB * MBANK * 4);
  float* g = (float*)alloc(KS * 4);
  float* rsz = (float*)alloc((size_t)NB * HW * HW * 4);
  float* tmp = (float*)alloc((size_t)NB * HW * HW * 4);
  signed char* emb_q = (signed char*)alloc((size_t)NROWPAD * DDIM);
  signed char* mem_q = (signed char*)alloc((size_t)NCOLPAD * DDIM);
  size_t full_need = off;

  bool fast = (ws_size >= full_need);

  if (fast) {
    convnorm8_kernel<<<NCOLPAD / 4, 256, 0, stream>>>(mem, mem_q, ynorm, MBANK, NCOLPAD);
    convnorm8_kernel<<<NROWPAD / 4, 256, 0, stream>>>(emb, emb_q, xnorm, NROWS, NROWPAD);
    mindist_mfma_kernel<<<NRT * NCT, 256, 0, stream>>>(emb_q, mem_q, xnorm, ynorm, cand);
    rerank_kernel<<<NROWS, 256, 0, stream>>>(emb, mem, xnorm, ynorm, cand, ps, loc);
    argmax_kernel<<<NB, 256, 0, stream>>>(ps, loc, bscore, bfrow, bnn);
  } else {
    rownorm_kernel<<<MBANK, 256, 0, stream>>>(mem, ynorm, MBANK);
    rownorm_kernel<<<NROWS, 256, 0, stream>>>(emb, xnorm, NROWS);
    unsigned long long* best = cand;  // alias
    init_u64_kernel<<<(NROWS + 255) / 256, 256, 0, stream>>>(best, NROWS);
    mindist_kernel<<<dim3(NROWS / BM, FCSPLIT), 256, 0, stream>>>(emb, mem, xnorm, ynorm,
                                                                  best);
    unpack_kernel<<<(NROWS + 255) / 256, 256, 0, stream>>>(best, ps, loc);
    argmax_kernel<<<NB, 256, 0, stream>>>(ps, loc, bscore, bfrow, bnn);
  }

  d2_kernel<<<1200, 256, 0, stream>>>(mem, ynorm, bnn, d2);
  topk_kernel<<<NB, 256, 0, stream>>>(emb, mem, xnorm, ynorm, d2, bscore, bfrow,
                                      out + (size_t)NB * HW * HW);
  gauss_kernel<<<1, 64, 0, stream>>>(g);
  resize_kernel<<<(NB * HW * HW + 255) / 256, 256, 0, stream>>>(ps, rsz);
  blurv_kernel<<<(NB * HW * HW + 255) / 256, 256, 0, stream>>>(rsz, g, tmp);
  blurh_kernel<<<(NB * HW * HW + 255) / 256, 256, 0, stream>>>(tmp, g, out);
}